// Round 4
// baseline (270.097 us; speedup 1.0000x reference)
//
#include <hip/hip_runtime.h>
#include <hip/hip_bf16.h>

// LinearCrossAttention fused pipeline for MI355X (gfx950).
// Key algebra: (1) conv1x1 commutes with bilinear resize -> K/V convs at 32x32.
//              (2) y = f_geo + bo + (Wo*KV^T)*Q / norm  -> avoids [B,N,256] QKV.
// All big GEMMs: bf16 MFMA (16x16x32), fp32 accumulate. Residual + GN in fp32.
// Fusions: ksum in resize; norm in qgemm (atomics); GN stats inline in gn.
// GEMM core: double-buffered LDS, reg-staged prefetch, ONE barrier per K-step.
// k_kv split-K = 16 chunks -> 512 blocks = 2 blocks/CU (2 waves/SIMD TLP).

#define B_ 8
#define C_ 256
#define H_ 64
#define W_ 64
#define N_ 4096
#define NS_ 1024
#define PIT 40   // LDS row pitch (bf16 elems): 80B row stride -> uniform b128 bank spread
#define LDSZ (4 * 128 * PIT)  // A0,B0,A1,B1
#define KVCH 16  // split-K chunks for k_kv

typedef unsigned short u16;
using bf16x8 = __attribute__((ext_vector_type(8))) short;
using f32x4 = __attribute__((ext_vector_type(4))) float;

__device__ inline u16 f2bf(float f) {
  unsigned u = __builtin_bit_cast(unsigned, f);
  unsigned r = (u + 0x7fffu + ((u >> 16) & 1u)) >> 16;
  return (u16)r;
}
__device__ inline float bf2f(u16 x) {
  return __builtin_bit_cast(float, ((unsigned)x) << 16);
}

// ---- core 128x128 NT GEMM tile: acc += A[128][K] * B[128][K]^T ----
// Double-buffered: one __syncthreads per K-step; global prefetch overlaps MFMA.
__device__ inline void gemm128_nt(const u16* __restrict__ At, const u16* __restrict__ Bt,
                                  int lda, int ldb, int k0, int k1,
                                  u16* __restrict__ lds, f32x4 acc[4][4])
{
  const int t = threadIdx.x;
  const int lane = t & 63;
  const int wave = t >> 6;
  const int wr = wave >> 1, wc = wave & 1;
  const int lr = lane & 15, lg = lane >> 4;
  const int sr = t >> 2, skv = t & 3;  // staging row (0..63), k-vec (0..3)
  const size_t aoff = (size_t)sr * lda + skv * 8;
  const size_t aoff2 = (size_t)(sr + 64) * lda + skv * 8;
  const size_t boff = (size_t)sr * ldb + skv * 8;
  const size_t boff2 = (size_t)(sr + 64) * ldb + skv * 8;
  const int woff = sr * PIT + skv * 8;
  u16* A0 = lds;
  u16* B0 = lds + 128 * PIT;
  u16* A1 = lds + 2 * 128 * PIT;
  u16* B1 = lds + 3 * 128 * PIT;

  {  // prologue: stage first K-slab into buf0
    uint4 a0 = *reinterpret_cast<const uint4*>(&At[aoff + k0]);
    uint4 a1 = *reinterpret_cast<const uint4*>(&At[aoff2 + k0]);
    uint4 b0 = *reinterpret_cast<const uint4*>(&Bt[boff + k0]);
    uint4 b1 = *reinterpret_cast<const uint4*>(&Bt[boff2 + k0]);
    *reinterpret_cast<uint4*>(&A0[woff]) = a0;
    *reinterpret_cast<uint4*>(&A0[woff + 64 * PIT]) = a1;
    *reinterpret_cast<uint4*>(&B0[woff]) = b0;
    *reinterpret_cast<uint4*>(&B0[woff + 64 * PIT]) = b1;
  }
  __syncthreads();
  int cur = 0;
  for (int k = k0; k < k1; k += 32) {
    uint4 na0, na1, nb0, nb1;
    const bool more = (k + 32) < k1;
    if (more) {  // issue next-slab loads early; latency hides under compute
      na0 = *reinterpret_cast<const uint4*>(&At[aoff + k + 32]);
      na1 = *reinterpret_cast<const uint4*>(&At[aoff2 + k + 32]);
      nb0 = *reinterpret_cast<const uint4*>(&Bt[boff + k + 32]);
      nb1 = *reinterpret_cast<const uint4*>(&Bt[boff2 + k + 32]);
    }
    const u16* Ar = cur ? A1 : A0;
    const u16* Br = cur ? B1 : B0;
    const u16* ab = &Ar[(wr * 64 + lr) * PIT + lg * 8];
    const u16* bb = &Br[(wc * 64 + lr) * PIT + lg * 8];
    bf16x8 af[4], bfr[4];
#pragma unroll
    for (int i = 0; i < 4; ++i) af[i] = *reinterpret_cast<const bf16x8*>(ab + i * 16 * PIT);
#pragma unroll
    for (int i = 0; i < 4; ++i) bfr[i] = *reinterpret_cast<const bf16x8*>(bb + i * 16 * PIT);
#pragma unroll
    for (int m = 0; m < 4; ++m)
#pragma unroll
      for (int n = 0; n < 4; ++n)
        acc[m][n] = __builtin_amdgcn_mfma_f32_16x16x32_bf16(af[m], bfr[n], acc[m][n], 0, 0, 0);
    if (more) {
      u16* Aw = cur ? A0 : A1;
      u16* Bw = cur ? B0 : B1;
      *reinterpret_cast<uint4*>(&Aw[woff]) = na0;
      *reinterpret_cast<uint4*>(&Aw[woff + 64 * PIT]) = na1;
      *reinterpret_cast<uint4*>(&Bw[woff]) = nb0;
      *reinterpret_cast<uint4*>(&Bw[woff + 64 * PIT]) = nb1;
    }
    __syncthreads();
    cur ^= 1;
  }
}

__device__ inline void zero_acc(f32x4 acc[4][4]) {
#pragma unroll
  for (int m = 0; m < 4; ++m)
#pragma unroll
    for (int n = 0; n < 4; ++n)
#pragma unroll
      for (int r = 0; r < 4; ++r) acc[m][n][r] = 0.f;
}

// ---- prep kernels ----
// in: [b][rows][cols] f32 -> out: [b][cols][rows] bf16
__global__ __launch_bounds__(256) void k_transpose_cast(const float* __restrict__ in,
                                                        u16* __restrict__ out, int rows, int cols)
{
  __shared__ float tile[32][33];
  int b = blockIdx.z;
  const float* src = in + (size_t)b * rows * cols;
  u16* dst = out + (size_t)b * rows * cols;
  int c0 = blockIdx.x * 32, r0 = blockIdx.y * 32;
  int tx = threadIdx.x & 31, ty = threadIdx.x >> 5;  // ty 0..7
#pragma unroll
  for (int i = 0; i < 32; i += 8)
    tile[ty + i][tx] = src[(size_t)(r0 + ty + i) * cols + (c0 + tx)];
  __syncthreads();
#pragma unroll
  for (int i = 0; i < 32; i += 8)
    dst[(size_t)(c0 + ty + i) * rows + (r0 + tx)] = f2bf(tile[tx][ty + i]);
}

// cast 4 weight matrices to bf16; also zero stats and init normv to eps
__global__ __launch_bounds__(256) void k_cast4(const float* __restrict__ w0, const float* __restrict__ w1,
                                               const float* __restrict__ w2, const float* __restrict__ w3,
                                               u16* o0, u16* o1, u16* o2, u16* o3,
                                               float* __restrict__ stats, float* __restrict__ normv)
{
  int i = blockIdx.x * 256 + threadIdx.x;  // 65536 elems
  o0[i] = f2bf(w0[i]); o1[i] = f2bf(w1[i]); o2[i] = f2bf(w2[i]); o3[i] = f2bf(w3[i]);
  if (i < 16) stats[i] = 0.f;
  if (i < B_ * N_) normv[i] = 1e-6f;
}

// ---- K/V conv at 32x32: Kpre[c][p] = Wk[c][ci]*f_sem[ci][p] + bk ----
__global__ __launch_bounds__(256) void k_semconv(const u16* __restrict__ fsemT,
                                                 const u16* __restrict__ Wk, const u16* __restrict__ Wv,
                                                 const float* __restrict__ bk, const float* __restrict__ bv,
                                                 u16* __restrict__ Kpre, u16* __restrict__ Vpre)
{
  __shared__ u16 lds[LDSZ];
  int b = blockIdx.z >> 1, sel = blockIdx.z & 1;
  int m0 = blockIdx.y * 128, n0 = blockIdx.x * 128;
  const u16* A = (sel ? Wv : Wk) + (size_t)m0 * C_;
  const u16* Bm = fsemT + (size_t)b * NS_ * C_ + (size_t)n0 * C_;
  const float* bias = sel ? bv : bk;
  u16* out = (sel ? Vpre : Kpre) + (size_t)b * C_ * NS_;
  f32x4 acc[4][4];
  zero_acc(acc);
  gemm128_nt(A, Bm, C_, C_, 0, C_, lds, acc);
  int lane = threadIdx.x & 63, wave = threadIdx.x >> 6;
  int wr = wave >> 1, wc = wave & 1, lr = lane & 15, lg = lane >> 4;
#pragma unroll
  for (int m = 0; m < 4; ++m)
#pragma unroll
    for (int r = 0; r < 4; ++r) {
      int row = m0 + wr * 64 + m * 16 + lg * 4 + r;
      float bi = bias[row];
#pragma unroll
      for (int n = 0; n < 4; ++n) {
        int col = n0 + wc * 64 + n * 16 + lr;
        out[(size_t)row * NS_ + col] = f2bf(acc[m][n][r] + bi);
      }
    }
}

// ---- bilinear 2x upsample (half-pixel) + phi on K; fused Ksum for K planes ----
__global__ __launch_bounds__(256) void k_resize(const u16* __restrict__ Kpre, const u16* __restrict__ Vpre,
                                                u16* __restrict__ Kbf, u16* __restrict__ Vbf,
                                                float* __restrict__ Ksum)
{
  int sel = blockIdx.y;
  const u16* src = (sel ? Vpre : Kpre) + (size_t)blockIdx.x * NS_;
  u16* dst = (sel ? Vbf : Kbf) + (size_t)blockIdx.x * N_;
  float s = 0.f;
  for (int i = threadIdx.x; i < N_; i += 256) {
    int yy = i >> 6, xx = i & 63;
    int yh = yy >> 1, xh = xx >> 1;
    int ys0, ys1, xs0, xs1; float wy0, wy1, wx0, wx1;
    if (yy & 1) { ys0 = yh; ys1 = yh < 31 ? yh + 1 : 31; wy0 = 0.75f; wy1 = 0.25f; }
    else        { ys0 = yh > 0 ? yh - 1 : 0; ys1 = yh;   wy0 = 0.25f; wy1 = 0.75f; }
    if (xx & 1) { xs0 = xh; xs1 = xh < 31 ? xh + 1 : 31; wx0 = 0.75f; wx1 = 0.25f; }
    else        { xs0 = xh > 0 ? xh - 1 : 0; xs1 = xh;   wx0 = 0.25f; wx1 = 0.75f; }
    float r0 = wx0 * bf2f(src[ys0 * 32 + xs0]) + wx1 * bf2f(src[ys0 * 32 + xs1]);
    float r1 = wx0 * bf2f(src[ys1 * 32 + xs0]) + wx1 * bf2f(src[ys1 * 32 + xs1]);
    float v = wy0 * r0 + wy1 * r1;
    if (!sel) { v = v > 0.f ? v + 1.f : __expf(v); s += v; }  // phi = elu+1
    dst[i] = f2bf(v);
  }
  if (!sel) {  // block-reduce K plane sum -> Ksum[b*C + c]
    __shared__ float red[256];
    red[threadIdx.x] = s; __syncthreads();
    for (int off = 128; off > 0; off >>= 1) {
      if (threadIdx.x < off) red[threadIdx.x] += red[threadIdx.x + off];
      __syncthreads();
    }
    if (threadIdx.x == 0) Ksum[blockIdx.x] = red[0];
  }
}

// ---- KV split-K: partial KV[c][d] over n-chunk (KVCH chunks of N_/KVCH) ----
__global__ __launch_bounds__(256) void k_kv(const u16* __restrict__ Kbf, const u16* __restrict__ Vbf,
                                            float* __restrict__ KVpart)
{
  __shared__ u16 lds[LDSZ];
  int tn = blockIdx.x, tm = blockIdx.y;
  int b = blockIdx.z >> 4, ch = blockIdx.z & 15;
  const int kspan = N_ / KVCH;  // 256
  const u16* A = Kbf + (size_t)b * C_ * N_ + (size_t)tm * 128 * N_;
  const u16* Bm = Vbf + (size_t)b * C_ * N_ + (size_t)tn * 128 * N_;
  f32x4 acc[4][4];
  zero_acc(acc);
  gemm128_nt(A, Bm, N_, N_, ch * kspan, ch * kspan + kspan, lds, acc);
  float* out = KVpart + ((size_t)(b * KVCH + ch) * 4 + tm * 2 + tn) * (128 * 128);
  int lane = threadIdx.x & 63, wave = threadIdx.x >> 6;
  int wr = wave >> 1, wc = wave & 1, lr = lane & 15, lg = lane >> 4;
#pragma unroll
  for (int m = 0; m < 4; ++m)
#pragma unroll
    for (int r = 0; r < 4; ++r)
#pragma unroll
      for (int n = 0; n < 4; ++n)
        out[(size_t)(wr * 64 + m * 16 + lg * 4 + r) * 128 + wc * 64 + n * 16 + lr] = acc[m][n][r];
}

__global__ __launch_bounds__(256) void k_kvred(const float* __restrict__ KVpart, u16* __restrict__ KVbf)
{
  int idx = blockIdx.x * 256 + threadIdx.x;  // B*C*C = 524288
  int b = idx >> 16, cd = idx & 65535;
  int c = cd >> 8, d = cd & 255;
  int tile = (c >> 7) * 2 + (d >> 7);
  int loc = (c & 127) * 128 + (d & 127);
  float s = 0.f;
#pragma unroll
  for (int ch = 0; ch < KVCH; ++ch)
    s += KVpart[((size_t)(b * KVCH + ch) * 4 + tile) * 16384 + loc];
  KVbf[idx] = f2bf(s);
}

// ---- M[o][c] = sum_d Wo[o][d] * KV[c][d] ----
__global__ __launch_bounds__(256) void k_mgemm(const u16* __restrict__ Wo, const u16* __restrict__ KVbf,
                                               u16* __restrict__ Mbf)
{
  __shared__ u16 lds[LDSZ];
  int tn = blockIdx.x, tm = blockIdx.y, b = blockIdx.z;
  const u16* A = Wo + (size_t)tm * 128 * C_;
  const u16* Bm = KVbf + (size_t)b * C_ * C_ + (size_t)tn * 128 * C_;
  f32x4 acc[4][4];
  zero_acc(acc);
  gemm128_nt(A, Bm, C_, C_, 0, C_, lds, acc);
  u16* out = Mbf + (size_t)b * C_ * C_;
  int lane = threadIdx.x & 63, wave = threadIdx.x >> 6;
  int wr = wave >> 1, wc = wave & 1, lr = lane & 15, lg = lane >> 4;
#pragma unroll
  for (int m = 0; m < 4; ++m)
#pragma unroll
    for (int r = 0; r < 4; ++r)
#pragma unroll
      for (int n = 0; n < 4; ++n)
        out[(size_t)(tm * 128 + wr * 64 + m * 16 + lg * 4 + r) * C_ +
            tn * 128 + wc * 64 + n * 16 + lr] = f2bf(acc[m][n][r]);
}

// ---- Qt[n][c] = phi(f_geoT[n][ci]*Wq[c][ci] + bq[c]); fused partial norm ----
__global__ __launch_bounds__(256) void k_qgemm(const u16* __restrict__ fgeoT, const u16* __restrict__ Wq,
                                               const float* __restrict__ bq, const float* __restrict__ Ksum,
                                               u16* __restrict__ Qt, float* __restrict__ normv)
{
  __shared__ u16 lds[LDSZ];
  int tc = blockIdx.x, tn = blockIdx.y, b = blockIdx.z;
  const u16* A = fgeoT + (size_t)b * N_ * C_ + (size_t)tn * 128 * C_;
  const u16* Bm = Wq + (size_t)tc * 128 * C_;
  f32x4 acc[4][4];
  zero_acc(acc);
  gemm128_nt(A, Bm, C_, C_, 0, C_, lds, acc);
  u16* out = Qt + (size_t)b * N_ * C_;
  int lane = threadIdx.x & 63, wave = threadIdx.x >> 6;
  int wr = wave >> 1, wc = wave & 1, lr = lane & 15, lg = lane >> 4;
  float bqv[4], ksv[4];
#pragma unroll
  for (int n = 0; n < 4; ++n) {
    int c = tc * 128 + wc * 64 + n * 16 + lr;
    bqv[n] = bq[c];
    ksv[n] = Ksum[b * C_ + c];
  }
  float pn[4][4];  // per-thread partial norm for each (m,r) row
#pragma unroll
  for (int m = 0; m < 4; ++m)
#pragma unroll
    for (int r = 0; r < 4; ++r) {
      int row = tn * 128 + wr * 64 + m * 16 + lg * 4 + r;  // n index
      float p = 0.f;
#pragma unroll
      for (int n = 0; n < 4; ++n) {
        float v = acc[m][n][r] + bqv[n];
        v = v > 0.f ? v + 1.f : __expf(v);  // phi
        out[(size_t)row * C_ + tc * 128 + wc * 64 + n * 16 + lr] = f2bf(v);
        p += v * ksv[n];
      }
      pn[m][r] = p;
    }
  // reduce over the 16 lr-lanes (xor 1,2,4,8 stays within an lg group)
#pragma unroll
  for (int m = 0; m < 4; ++m)
#pragma unroll
    for (int r = 0; r < 4; ++r) {
      float p = pn[m][r];
      p += __shfl_xor(p, 1); p += __shfl_xor(p, 2);
      p += __shfl_xor(p, 4); p += __shfl_xor(p, 8);
      pn[m][r] = p;
    }
  if (lr == 0) {
    float* nb = normv + (size_t)b * N_;
#pragma unroll
    for (int m = 0; m < 4; ++m)
#pragma unroll
      for (int r = 0; r < 4; ++r) {
        int row = tn * 128 + wr * 64 + m * 16 + lg * 4 + r;
        atomicAdd(&nb[row], pn[m][r]);
      }
  }
}

// ---- y[o][n] = f_geo + bo + (M*Q)/norm ; accumulate GN partial stats ----
__global__ __launch_bounds__(256) void k_final(const u16* __restrict__ Mbf, const u16* __restrict__ Qt,
                                               const float* __restrict__ fgeo, const float* __restrict__ bo,
                                               const float* __restrict__ normv,
                                               float* __restrict__ y, float* __restrict__ stats)
{
  __shared__ u16 lds[LDSZ];
  int tn = blockIdx.x, tm = blockIdx.y, b = blockIdx.z;
  const u16* A = Mbf + (size_t)b * C_ * C_ + (size_t)tm * 128 * C_;
  const u16* Bm = Qt + (size_t)b * N_ * C_ + (size_t)tn * 128 * C_;
  f32x4 acc[4][4];
  zero_acc(acc);
  gemm128_nt(A, Bm, C_, C_, 0, C_, lds, acc);
  int lane = threadIdx.x & 63, wave = threadIdx.x >> 6;
  int wr = wave >> 1, wc = wave & 1, lr = lane & 15, lg = lane >> 4;
  int m0 = tm * 128, n0 = tn * 128;
  const float* nrm = normv + (size_t)b * N_;
  float nv[4];
#pragma unroll
  for (int n = 0; n < 4; ++n) nv[n] = nrm[n0 + wc * 64 + n * 16 + lr];
  const float* fg = fgeo + (size_t)b * C_ * N_;
  float* yb = y + (size_t)b * C_ * N_;
  float ssum = 0.f, ssq = 0.f;
#pragma unroll
  for (int m = 0; m < 4; ++m)
#pragma unroll
    for (int r = 0; r < 4; ++r) {
      int row = m0 + wr * 64 + m * 16 + lg * 4 + r;
      float bov = bo[row];
#pragma unroll
      for (int n = 0; n < 4; ++n) {
        int col = n0 + wc * 64 + n * 16 + lr;
        float val = fg[(size_t)row * N_ + col] + bov + acc[m][n][r] / nv[n];
        yb[(size_t)row * N_ + col] = val;
        ssum += val; ssq += val * val;
      }
    }
#pragma unroll
  for (int off = 1; off < 64; off <<= 1) {
    ssum += __shfl_xor(ssum, off);
    ssq += __shfl_xor(ssq, off);
  }
  if (lane == 0) {
    atomicAdd(&stats[b * 2], ssum);
    atomicAdd(&stats[b * 2 + 1], ssq);
  }
}

// ---- GN affine apply; mu/rsqrt inline from stats; 2 float4 per thread ----
__global__ __launch_bounds__(256) void k_gn(float* __restrict__ y, const float* __restrict__ stats,
                                            const float* __restrict__ gnw, const float* __restrict__ gnb)
{
  int idx = blockIdx.x * 256 + threadIdx.x;  // 8-float index
  int elem = idx * 8;
  int b = elem >> 20;           // C*N = 2^20
  int o = (elem >> 12) & 255;   // N = 2^12 (8 | 4096 -> both float4s same channel)
  const float cnt = (float)C_ * (float)N_;
  float mu = stats[b * 2] / cnt;
  float var = stats[b * 2 + 1] / cnt - mu * mu;
  float rs = rsqrtf(var + 1e-5f);
  float sc = gnw[o] * rs;
  float sh = gnb[o] - mu * sc;
  float4* p = reinterpret_cast<float4*>(y) + idx * 2;
  float4 v0 = p[0], v1 = p[1];
  v0.x = v0.x * sc + sh; v0.y = v0.y * sc + sh; v0.z = v0.z * sc + sh; v0.w = v0.w * sc + sh;
  v1.x = v1.x * sc + sh; v1.y = v1.y * sc + sh; v1.z = v1.z * sc + sh; v1.w = v1.w * sc + sh;
  p[0] = v0; p[1] = v1;
}

extern "C" void kernel_launch(void* const* d_in, const int* in_sizes, int n_in,
                              void* d_out, int out_size, void* d_ws, size_t ws_size,
                              hipStream_t stream)
{
  const float* f_geo = (const float*)d_in[0];
  const float* f_sem = (const float*)d_in[1];
  const float* Wq = (const float*)d_in[2];
  const float* bq = (const float*)d_in[3];
  const float* Wk = (const float*)d_in[4];
  const float* bk = (const float*)d_in[5];
  const float* Wv = (const float*)d_in[6];
  const float* bv = (const float*)d_in[7];
  const float* Wo = (const float*)d_in[8];
  const float* bo = (const float*)d_in[9];
  const float* gnw = (const float*)d_in[10];
  const float* gnb = (const float*)d_in[11];
  float* y = (float*)d_out;

  char* w = (char*)d_ws;
  auto alloc = [&](size_t bytes) { char* p = w; w += (bytes + 255) & ~(size_t)255; return p; };
  u16* fsemT = (u16*)alloc((size_t)B_ * NS_ * C_ * 2);
  u16* fgeoT = (u16*)alloc((size_t)B_ * N_ * C_ * 2);
  u16* Wqb = (u16*)alloc(65536 * 2);
  u16* Wkb = (u16*)alloc(65536 * 2);
  u16* Wvb = (u16*)alloc(65536 * 2);
  u16* Wob = (u16*)alloc(65536 * 2);
  u16* Kpre = (u16*)alloc((size_t)B_ * C_ * NS_ * 2);
  u16* Vpre = (u16*)alloc((size_t)B_ * C_ * NS_ * 2);
  u16* Kbf = (u16*)alloc((size_t)B_ * C_ * N_ * 2);
  u16* Vbf = (u16*)alloc((size_t)B_ * C_ * N_ * 2);
  float* Ksum = (float*)alloc((size_t)B_ * C_ * 4);
  float* KVpart = (float*)alloc((size_t)B_ * KVCH * 4 * 16384 * 4);
  u16* KVbf = (u16*)alloc((size_t)B_ * C_ * C_ * 2);
  u16* Mbf = (u16*)alloc((size_t)B_ * C_ * C_ * 2);
  u16* Qt = (u16*)alloc((size_t)B_ * N_ * C_ * 2);
  float* normv = (float*)alloc((size_t)B_ * N_ * 4);
  float* stats = (float*)alloc(256);

  k_transpose_cast<<<dim3(NS_ / 32, C_ / 32, B_), 256, 0, stream>>>(f_sem, fsemT, C_, NS_);
  k_transpose_cast<<<dim3(N_ / 32, C_ / 32, B_), 256, 0, stream>>>(f_geo, fgeoT, C_, N_);
  k_cast4<<<dim3(256), 256, 0, stream>>>(Wq, Wk, Wv, Wo, Wqb, Wkb, Wvb, Wob, stats, normv);
  k_semconv<<<dim3(8, 2, 16), 256, 0, stream>>>(fsemT, Wkb, Wvb, bk, bv, Kpre, Vpre);
  k_resize<<<dim3(B_ * C_, 2), 256, 0, stream>>>(Kpre, Vpre, Kbf, Vbf, Ksum);
  k_kv<<<dim3(2, 2, B_ * KVCH), 256, 0, stream>>>(Kbf, Vbf, KVpart);
  k_kvred<<<dim3(2048), 256, 0, stream>>>(KVpart, KVbf);
  k_mgemm<<<dim3(2, 2, B_), 256, 0, stream>>>(Wob, KVbf, Mbf);
  k_qgemm<<<dim3(2, 32, B_), 256, 0, stream>>>(fgeoT, Wqb, bq, Ksum, Qt, normv);
  k_final<<<dim3(32, 2, B_), 256, 0, stream>>>(Mbf, Qt, f_geo, bo, normv, y, stats);
  k_gn<<<dim3(B_ * C_ * N_ / 8 / 256), 256, 0, stream>>>(y, stats, gnw, gnb);
}

// Round 5
// 266.122 us; speedup vs baseline: 1.0149x; 1.0149x over previous
//
#include <hip/hip_runtime.h>
#include <hip/hip_bf16.h>

// LinearCrossAttention fused pipeline for MI355X (gfx950).
// Algebra: (1) conv1x1 commutes with bilinear resize -> K/V convs at 32x32.
//          (2) y = f_geo + bo + (Wo*KV^T)*Q / norm  -> avoids [B,N,256] QKV.
// GEMMs: bf16 MFMA 16x16x32, fp32 acc. m97 staging: global_load_lds width=16
// into linear [128][32] LDS, 2-barrier K-loop. Epilogues: LDS-staged [64][132]
// fp32 then fully-coalesced float4/ushort4 global I/O.

#define B_ 8
#define C_ 256
#define N_ 4096
#define NS_ 1024
#define KVCH 16

typedef unsigned short u16;
using bf16x8 = __attribute__((ext_vector_type(8))) short;
using f32x4 = __attribute__((ext_vector_type(4))) float;

__device__ inline u16 f2bf(float f) {
  unsigned u = __builtin_bit_cast(unsigned, f);
  unsigned r = (u + 0x7fffu + ((u >> 16) & 1u)) >> 16;
  return (u16)r;
}
__device__ inline float bf2f(u16 x) {
  return __builtin_bit_cast(float, ((unsigned)x) << 16);
}

__device__ __forceinline__ void gl_lds16(const u16* g, u16* l) {
  __builtin_amdgcn_global_load_lds((const __attribute__((address_space(1))) void*)g,
                                   (__attribute__((address_space(3))) void*)l, 16, 0, 0);
}

// ---- core 128x128 NT GEMM: acc += A[128][K] * B[128][K]^T (K-range [k0,k1)) ----
// LDS tiles Ab,Bb: [128][32] linear bf16 (8KB each). global_load_lds staging.
__device__ inline void gemm128_nt(const u16* __restrict__ At, const u16* __restrict__ Bt,
                                  int lda, int ldb, int k0, int k1,
                                  u16* __restrict__ lds, f32x4 acc[4][4])
{
  const int t = threadIdx.x;
  const int lane = t & 63, wave = t >> 6;
  const int wr = wave >> 1, wc = wave & 1;
  const int lr = lane & 15, lg = lane >> 4;
  const int sr = t >> 2, skv = (t & 3) * 8;   // staging row 0..63, elem offset in 32-col slab
  u16* Ab = lds;
  u16* Bb = lds + 128 * 32;
  const u16* gA0 = At + (size_t)sr * lda + skv;
  const u16* gA1 = At + (size_t)(sr + 64) * lda + skv;
  const u16* gB0 = Bt + (size_t)sr * ldb + skv;
  const u16* gB1 = Bt + (size_t)(sr + 64) * ldb + skv;
  // wave-uniform LDS dests; HW writes lane l at base + l*16B (= 16 rows/wave, linear)
  u16* dA0 = Ab + wave * 512;
  u16* dA1 = Ab + 2048 + wave * 512;
  u16* dB0 = Bb + wave * 512;
  u16* dB1 = Bb + 2048 + wave * 512;
  const u16* ap = Ab + (wr * 64 + lr) * 32 + lg * 8;
  const u16* bp = Bb + (wc * 64 + lr) * 32 + lg * 8;
  for (int k = k0; k < k1; k += 32) {
    gl_lds16(gA0 + k, dA0);
    gl_lds16(gA1 + k, dA1);
    gl_lds16(gB0 + k, dB0);
    gl_lds16(gB1 + k, dB1);
    __syncthreads();  // drains vmcnt -> LDS tiles ready
    bf16x8 af[4], bfr[4];
#pragma unroll
    for (int i = 0; i < 4; ++i) af[i] = *reinterpret_cast<const bf16x8*>(ap + i * 16 * 32);
#pragma unroll
    for (int i = 0; i < 4; ++i) bfr[i] = *reinterpret_cast<const bf16x8*>(bp + i * 16 * 32);
#pragma unroll
    for (int m = 0; m < 4; ++m)
#pragma unroll
      for (int n = 0; n < 4; ++n)
        acc[m][n] = __builtin_amdgcn_mfma_f32_16x16x32_bf16(af[m], bfr[n], acc[m][n], 0, 0, 0);
    __syncthreads();  // protect tiles before next-iter overwrite
  }
}

__device__ inline void zero_acc(f32x4 acc[4][4]) {
#pragma unroll
  for (int m = 0; m < 4; ++m)
#pragma unroll
    for (int n = 0; n < 4; ++n)
#pragma unroll
      for (int r = 0; r < 4; ++r) acc[m][n][r] = 0.f;
}

// stage one 64-row half (wr==h waves) of acc into eplds[64][132] fp32
__device__ inline void ep_stage_half(const f32x4 acc[4][4], float* eplds, int h,
                                     int wr, int wc, int lr, int lg)
{
  if (wr == h) {
#pragma unroll
    for (int m = 0; m < 4; ++m)
#pragma unroll
      for (int n = 0; n < 4; ++n)
#pragma unroll
        for (int r = 0; r < 4; ++r)
          eplds[(m * 16 + lg * 4 + r) * 132 + wc * 64 + n * 16 + lr] = acc[m][n][r];
  }
}

// ---- prep kernels ----
__global__ __launch_bounds__(256) void k_transpose_cast(const float* __restrict__ in,
                                                        u16* __restrict__ out, int rows, int cols)
{
  __shared__ float tile[32][33];
  int b = blockIdx.z;
  const float* src = in + (size_t)b * rows * cols;
  u16* dst = out + (size_t)b * rows * cols;
  int c0 = blockIdx.x * 32, r0 = blockIdx.y * 32;
  int tx = threadIdx.x & 31, ty = threadIdx.x >> 5;
#pragma unroll
  for (int i = 0; i < 32; i += 8)
    tile[ty + i][tx] = src[(size_t)(r0 + ty + i) * cols + (c0 + tx)];
  __syncthreads();
#pragma unroll
  for (int i = 0; i < 32; i += 8)
    dst[(size_t)(c0 + ty + i) * rows + (r0 + tx)] = f2bf(tile[tx][ty + i]);
}

__global__ __launch_bounds__(256) void k_cast4(const float* __restrict__ w0, const float* __restrict__ w1,
                                               const float* __restrict__ w2, const float* __restrict__ w3,
                                               u16* o0, u16* o1, u16* o2, u16* o3,
                                               float* __restrict__ stats, float* __restrict__ normv)
{
  int i = blockIdx.x * 256 + threadIdx.x;
  o0[i] = f2bf(w0[i]); o1[i] = f2bf(w1[i]); o2[i] = f2bf(w2[i]); o3[i] = f2bf(w3[i]);
  if (i < 16) stats[i] = 0.f;
  if (i < B_ * N_) normv[i] = 1e-6f;
}

// ---- K/V conv at 32x32 ----
__global__ __launch_bounds__(256) void k_semconv(const u16* __restrict__ fsemT,
                                                 const u16* __restrict__ Wk, const u16* __restrict__ Wv,
                                                 const float* __restrict__ bk, const float* __restrict__ bv,
                                                 u16* __restrict__ Kpre, u16* __restrict__ Vpre)
{
  __shared__ u16 glds[2 * 128 * 32];
  __shared__ float eplds[64 * 132];
  int b = blockIdx.z >> 1, sel = blockIdx.z & 1;
  int m0 = blockIdx.y * 128, n0 = blockIdx.x * 128;
  const u16* A = (sel ? Wv : Wk) + (size_t)m0 * C_;
  const u16* Bm = fsemT + (size_t)b * NS_ * C_ + (size_t)n0 * C_;
  const float* bias = sel ? bv : bk;
  u16* out = (sel ? Vpre : Kpre) + (size_t)b * C_ * NS_;
  f32x4 acc[4][4];
  zero_acc(acc);
  gemm128_nt(A, Bm, C_, C_, 0, C_, glds, acc);
  int t = threadIdx.x, lane = t & 63, wave = t >> 6;
  int wr = wave >> 1, wc = wave & 1, lr = lane & 15, lg = lane >> 4;
  for (int h = 0; h < 2; ++h) {
    __syncthreads();
    ep_stage_half(acc, eplds, h, wr, wc, lr, lg);
    __syncthreads();
#pragma unroll
    for (int it = 0; it < 8; ++it) {
      int rloc = it * 8 + (t >> 5), cloc = (t & 31) * 4;
      int row = m0 + h * 64 + rloc;
      float4 a = *(const float4*)&eplds[rloc * 132 + cloc];
      float bi = bias[row];
      ushort4 o;
      o.x = f2bf(a.x + bi); o.y = f2bf(a.y + bi); o.z = f2bf(a.z + bi); o.w = f2bf(a.w + bi);
      *(ushort4*)&out[(size_t)row * NS_ + n0 + cloc] = o;
    }
  }
}

// ---- bilinear 2x upsample + phi on K; fused Ksum ----
__global__ __launch_bounds__(256) void k_resize(const u16* __restrict__ Kpre, const u16* __restrict__ Vpre,
                                                u16* __restrict__ Kbf, u16* __restrict__ Vbf,
                                                float* __restrict__ Ksum)
{
  int sel = blockIdx.y;
  const u16* src = (sel ? Vpre : Kpre) + (size_t)blockIdx.x * NS_;
  u16* dst = (sel ? Vbf : Kbf) + (size_t)blockIdx.x * N_;
  float s = 0.f;
  for (int i = threadIdx.x; i < N_; i += 256) {
    int yy = i >> 6, xx = i & 63;
    int yh = yy >> 1, xh = xx >> 1;
    int ys0, ys1, xs0, xs1; float wy0, wy1, wx0, wx1;
    if (yy & 1) { ys0 = yh; ys1 = yh < 31 ? yh + 1 : 31; wy0 = 0.75f; wy1 = 0.25f; }
    else        { ys0 = yh > 0 ? yh - 1 : 0; ys1 = yh;   wy0 = 0.25f; wy1 = 0.75f; }
    if (xx & 1) { xs0 = xh; xs1 = xh < 31 ? xh + 1 : 31; wx0 = 0.75f; wx1 = 0.25f; }
    else        { xs0 = xh > 0 ? xh - 1 : 0; xs1 = xh;   wx0 = 0.25f; wx1 = 0.75f; }
    float r0 = wx0 * bf2f(src[ys0 * 32 + xs0]) + wx1 * bf2f(src[ys0 * 32 + xs1]);
    float r1 = wx0 * bf2f(src[ys1 * 32 + xs0]) + wx1 * bf2f(src[ys1 * 32 + xs1]);
    float v = wy0 * r0 + wy1 * r1;
    if (!sel) { v = v > 0.f ? v + 1.f : __expf(v); s += v; }
    dst[i] = f2bf(v);
  }
  if (!sel) {
    __shared__ float red[256];
    red[threadIdx.x] = s; __syncthreads();
    for (int off = 128; off > 0; off >>= 1) {
      if (threadIdx.x < off) red[threadIdx.x] += red[threadIdx.x + off];
      __syncthreads();
    }
    if (threadIdx.x == 0) Ksum[blockIdx.x] = red[0];
  }
}

// ---- KV split-K partials ----
__global__ __launch_bounds__(256) void k_kv(const u16* __restrict__ Kbf, const u16* __restrict__ Vbf,
                                            float* __restrict__ KVpart)
{
  __shared__ u16 glds[2 * 128 * 32];
  __shared__ float eplds[64 * 132];
  int tn = blockIdx.x, tm = blockIdx.y;
  int b = blockIdx.z >> 4, ch = blockIdx.z & 15;
  const int kspan = N_ / KVCH;
  const u16* A = Kbf + (size_t)b * C_ * N_ + (size_t)tm * 128 * N_;
  const u16* Bm = Vbf + (size_t)b * C_ * N_ + (size_t)tn * 128 * N_;
  f32x4 acc[4][4];
  zero_acc(acc);
  gemm128_nt(A, Bm, N_, N_, ch * kspan, ch * kspan + kspan, glds, acc);
  float* out = KVpart + ((size_t)(b * KVCH + ch) * 4 + tm * 2 + tn) * (128 * 128);
  int t = threadIdx.x, lane = t & 63, wave = t >> 6;
  int wr = wave >> 1, wc = wave & 1, lr = lane & 15, lg = lane >> 4;
  for (int h = 0; h < 2; ++h) {
    __syncthreads();
    ep_stage_half(acc, eplds, h, wr, wc, lr, lg);
    __syncthreads();
#pragma unroll
    for (int it = 0; it < 8; ++it) {
      int rloc = it * 8 + (t >> 5), cloc = (t & 31) * 4;
      float4 a = *(const float4*)&eplds[rloc * 132 + cloc];
      *(float4*)&out[(size_t)(h * 64 + rloc) * 128 + cloc] = a;
    }
  }
}

__global__ __launch_bounds__(256) void k_kvred(const float* __restrict__ KVpart, u16* __restrict__ KVbf)
{
  int idx = blockIdx.x * 256 + threadIdx.x;  // B*C*C
  int b = idx >> 16, cd = idx & 65535;
  int c = cd >> 8, d = cd & 255;
  int tile = (c >> 7) * 2 + (d >> 7);
  int loc = (c & 127) * 128 + (d & 127);
  float s = 0.f;
#pragma unroll
  for (int ch = 0; ch < KVCH; ++ch)
    s += KVpart[((size_t)(b * KVCH + ch) * 4 + tile) * 16384 + loc];
  KVbf[idx] = f2bf(s);
}

// ---- M[o][c] = sum_d Wo[o][d] * KV[c][d] ----
__global__ __launch_bounds__(256) void k_mgemm(const u16* __restrict__ Wo, const u16* __restrict__ KVbf,
                                               u16* __restrict__ Mbf)
{
  __shared__ u16 glds[2 * 128 * 32];
  __shared__ float eplds[64 * 132];
  int tn = blockIdx.x, tm = blockIdx.y, b = blockIdx.z;
  const u16* A = Wo + (size_t)tm * 128 * C_;
  const u16* Bm = KVbf + (size_t)b * C_ * C_ + (size_t)tn * 128 * C_;
  f32x4 acc[4][4];
  zero_acc(acc);
  gemm128_nt(A, Bm, C_, C_, 0, C_, glds, acc);
  u16* out = Mbf + (size_t)b * C_ * C_;
  int t = threadIdx.x, lane = t & 63, wave = t >> 6;
  int wr = wave >> 1, wc = wave & 1, lr = lane & 15, lg = lane >> 4;
  for (int h = 0; h < 2; ++h) {
    __syncthreads();
    ep_stage_half(acc, eplds, h, wr, wc, lr, lg);
    __syncthreads();
#pragma unroll
    for (int it = 0; it < 8; ++it) {
      int rloc = it * 8 + (t >> 5), cloc = (t & 31) * 4;
      int row = tm * 128 + h * 64 + rloc;
      float4 a = *(const float4*)&eplds[rloc * 132 + cloc];
      ushort4 o;
      o.x = f2bf(a.x); o.y = f2bf(a.y); o.z = f2bf(a.z); o.w = f2bf(a.w);
      *(ushort4*)&out[(size_t)row * C_ + tn * 128 + cloc] = o;
    }
  }
}

// ---- Qt[n][c] = phi(fgeoT*Wq + bq); fused norm partials ----
__global__ __launch_bounds__(256) void k_qgemm(const u16* __restrict__ fgeoT, const u16* __restrict__ Wq,
                                               const float* __restrict__ bq, const float* __restrict__ Ksum,
                                               u16* __restrict__ Qt, float* __restrict__ normv)
{
  __shared__ u16 glds[2 * 128 * 32];
  __shared__ float eplds[64 * 132];
  int tc = blockIdx.x, tn = blockIdx.y, b = blockIdx.z;
  const u16* A = fgeoT + (size_t)b * N_ * C_ + (size_t)tn * 128 * C_;
  const u16* Bm = Wq + (size_t)tc * 128 * C_;
  f32x4 acc[4][4];
  zero_acc(acc);
  gemm128_nt(A, Bm, C_, C_, 0, C_, glds, acc);
  u16* out = Qt + (size_t)b * N_ * C_;
  float* nb = normv + (size_t)b * N_;
  int t = threadIdx.x, lane = t & 63, wave = t >> 6;
  int wr = wave >> 1, wc = wave & 1, lr = lane & 15, lg = lane >> 4;
  for (int h = 0; h < 2; ++h) {
    __syncthreads();
    ep_stage_half(acc, eplds, h, wr, wc, lr, lg);
    __syncthreads();
#pragma unroll
    for (int it = 0; it < 8; ++it) {
      int rloc = it * 8 + (t >> 5), cloc = (t & 31) * 4;
      int row = tn * 128 + h * 64 + rloc;   // n index
      int col = tc * 128 + cloc;            // c index
      float4 a = *(const float4*)&eplds[rloc * 132 + cloc];
      float4 bqv = *(const float4*)&bq[col];
      float4 ks = *(const float4*)&Ksum[b * C_ + col];
      float v0 = a.x + bqv.x; v0 = v0 > 0.f ? v0 + 1.f : __expf(v0);
      float v1 = a.y + bqv.y; v1 = v1 > 0.f ? v1 + 1.f : __expf(v1);
      float v2 = a.z + bqv.z; v2 = v2 > 0.f ? v2 + 1.f : __expf(v2);
      float v3 = a.w + bqv.w; v3 = v3 > 0.f ? v3 + 1.f : __expf(v3);
      ushort4 o;
      o.x = f2bf(v0); o.y = f2bf(v1); o.z = f2bf(v2); o.w = f2bf(v3);
      *(ushort4*)&out[(size_t)row * C_ + col] = o;
      float p = v0 * ks.x + v1 * ks.y + v2 * ks.z + v3 * ks.w;
      p += __shfl_xor(p, 1); p += __shfl_xor(p, 2);
      p += __shfl_xor(p, 4); p += __shfl_xor(p, 8); p += __shfl_xor(p, 16);
      if ((t & 31) == 0) atomicAdd(&nb[row], p);
    }
  }
}

// ---- y = f_geo + bo + (M*Q)/norm ; GN partial stats ----
__global__ __launch_bounds__(256) void k_final(const u16* __restrict__ Mbf, const u16* __restrict__ Qt,
                                               const float* __restrict__ fgeo, const float* __restrict__ bo,
                                               const float* __restrict__ normv,
                                               float* __restrict__ y, float* __restrict__ stats)
{
  __shared__ u16 glds[2 * 128 * 32];
  __shared__ float eplds[64 * 132];
  int tn = blockIdx.x, tm = blockIdx.y, b = blockIdx.z;
  const u16* A = Mbf + (size_t)b * C_ * C_ + (size_t)tm * 128 * C_;
  const u16* Bm = Qt + (size_t)b * N_ * C_ + (size_t)tn * 128 * C_;
  f32x4 acc[4][4];
  zero_acc(acc);
  gemm128_nt(A, Bm, C_, C_, 0, C_, glds, acc);
  const float* nrm = normv + (size_t)b * N_;
  const float* fg = fgeo + (size_t)b * C_ * N_;
  float* yb = y + (size_t)b * C_ * N_;
  int t = threadIdx.x, lane = t & 63, wave = t >> 6;
  int wr = wave >> 1, wc = wave & 1, lr = lane & 15, lg = lane >> 4;
  float ssum = 0.f, ssq = 0.f;
  for (int h = 0; h < 2; ++h) {
    __syncthreads();
    ep_stage_half(acc, eplds, h, wr, wc, lr, lg);
    __syncthreads();
#pragma unroll
    for (int it = 0; it < 8; ++it) {
      int rloc = it * 8 + (t >> 5), cloc = (t & 31) * 4;
      int row = tm * 128 + h * 64 + rloc;
      int col = tn * 128 + cloc;
      float4 a = *(const float4*)&eplds[rloc * 132 + cloc];
      float4 nv = *(const float4*)&nrm[col];
      float4 f = *(const float4*)&fg[(size_t)row * N_ + col];
      float bov = bo[row];
      float4 v;
      v.x = f.x + bov + a.x / nv.x;
      v.y = f.y + bov + a.y / nv.y;
      v.z = f.z + bov + a.z / nv.z;
      v.w = f.w + bov + a.w / nv.w;
      *(float4*)&yb[(size_t)row * N_ + col] = v;
      ssum += v.x + v.y + v.z + v.w;
      ssq += v.x * v.x + v.y * v.y + v.z * v.z + v.w * v.w;
    }
  }
#pragma unroll
  for (int off = 1; off < 64; off <<= 1) {
    ssum += __shfl_xor(ssum, off);
    ssq += __shfl_xor(ssq, off);
  }
  if (lane == 0) {
    atomicAdd(&stats[b * 2], ssum);
    atomicAdd(&stats[b * 2 + 1], ssq);
  }
}

// ---- GN affine apply ----
__global__ __launch_bounds__(256) void k_gn(float* __restrict__ y, const float* __restrict__ stats,
                                            const float* __restrict__ gnw, const float* __restrict__ gnb)
{
  int idx = blockIdx.x * 256 + threadIdx.x;
  int elem = idx * 8;
  int b = elem >> 20;
  int o = (elem >> 12) & 255;
  const float cnt = (float)C_ * (float)N_;
  float mu = stats[b * 2] / cnt;
  float var = stats[b * 2 + 1] / cnt - mu * mu;
  float rs = rsqrtf(var + 1e-5f);
  float sc = gnw[o] * rs;
  float sh = gnb[o] - mu * sc;
  float4* p = reinterpret_cast<float4*>(y) + idx * 2;
  float4 v0 = p[0], v1 = p[1];
  v0.x = v0.x * sc + sh; v0.y = v0.y * sc + sh; v0.z = v0.z * sc + sh; v0.w = v0.w * sc + sh;
  v1.x = v1.x * sc + sh; v1.y = v1.y * sc + sh; v1.z = v1.z * sc + sh; v1.w = v1.w * sc + sh;
  p[0] = v0; p[1] = v1;
}

extern "C" void kernel_launch(void* const* d_in, const int* in_sizes, int n_in,
                              void* d_out, int out_size, void* d_ws, size_t ws_size,
                              hipStream_t stream)
{
  const float* f_geo = (const float*)d_in[0];
  const float* f_sem = (const float*)d_in[1];
  const float* Wq = (const float*)d_in[2];
  const float* bq = (const float*)d_in[3];
  const float* Wk = (const float*)d_in[4];
  const float* bk = (const float*)d_in[5];
  const float* Wv = (const float*)d_in[6];
  const float* bv = (const float*)d_in[7];
  const float* Wo = (const float*)d_in[8];
  const float* bo = (const float*)d_in[9];
  const float* gnw = (const float*)d_in[10];
  const float* gnb = (const float*)d_in[11];
  float* y = (float*)d_out;

  char* w = (char*)d_ws;
  auto alloc = [&](size_t bytes) { char* p = w; w += (bytes + 255) & ~(size_t)255; return p; };
  u16* fsemT = (u16*)alloc((size_t)B_ * NS_ * C_ * 2);
  u16* fgeoT = (u16*)alloc((size_t)B_ * N_ * C_ * 2);
  u16* Wqb = (u16*)alloc(65536 * 2);
  u16* Wkb = (u16*)alloc(65536 * 2);
  u16* Wvb = (u16*)alloc(65536 * 2);
  u16* Wob = (u16*)alloc(65536 * 2);
  u16* Kpre = (u16*)alloc((size_t)B_ * C_ * NS_ * 2);
  u16* Vpre = (u16*)alloc((size_t)B_ * C_ * NS_ * 2);
  u16* Kbf = (u16*)alloc((size_t)B_ * C_ * N_ * 2);
  u16* Vbf = (u16*)alloc((size_t)B_ * C_ * N_ * 2);
  float* Ksum = (float*)alloc((size_t)B_ * C_ * 4);
  float* KVpart = (float*)alloc((size_t)B_ * KVCH * 4 * 16384 * 4);
  u16* KVbf = (u16*)alloc((size_t)B_ * C_ * C_ * 2);
  u16* Mbf = (u16*)alloc((size_t)B_ * C_ * C_ * 2);
  u16* Qt = (u16*)alloc((size_t)B_ * N_ * C_ * 2);
  float* normv = (float*)alloc((size_t)B_ * N_ * 4);
  float* stats = (float*)alloc(256);

  k_transpose_cast<<<dim3(NS_ / 32, C_ / 32, B_), 256, 0, stream>>>(f_sem, fsemT, C_, NS_);
  k_transpose_cast<<<dim3(N_ / 32, C_ / 32, B_), 256, 0, stream>>>(f_geo, fgeoT, C_, N_);
  k_cast4<<<dim3(256), 256, 0, stream>>>(Wq, Wk, Wv, Wo, Wqb, Wkb, Wvb, Wob, stats, normv);
  k_semconv<<<dim3(8, 2, 16), 256, 0, stream>>>(fsemT, Wkb, Wvb, bk, bv, Kpre, Vpre);
  k_resize<<<dim3(B_ * C_, 2), 256, 0, stream>>>(Kpre, Vpre, Kbf, Vbf, Ksum);
  k_kv<<<dim3(2, 2, B_ * KVCH), 256, 0, stream>>>(Kbf, Vbf, KVpart);
  k_kvred<<<dim3(2048), 256, 0, stream>>>(KVpart, KVbf);
  k_mgemm<<<dim3(2, 2, B_), 256, 0, stream>>>(Wob, KVbf, Mbf);
  k_qgemm<<<dim3(2, 32, B_), 256, 0, stream>>>(fgeoT, Wqb, bq, Ksum, Qt, normv);
  k_final<<<dim3(32, 2, B_), 256, 0, stream>>>(Mbf, Qt, f_geo, bo, normv, y, stats);
  k_gn<<<dim3(B_ * C_ * N_ / 8 / 256), 256, 0, stream>>>(y, stats, gnw, gnb);
}